// Round 1
// baseline (200.101 us; speedup 1.0000x reference)
//
#include <hip/hip_runtime.h>
#include <hip/hip_bf16.h>
#include <stdint.h>

#define LOG2E 1.44269504088896340736f

typedef float f32x4 __attribute__((ext_vector_type(4)));
typedef __bf16 bf16x8 __attribute__((ext_vector_type(8)));

__device__ __forceinline__ void g2lds16(const void* g, void* l) {
  __builtin_amdgcn_global_load_lds(
      (__attribute__((address_space(1))) unsigned int*)g,
      (__attribute__((address_space(3))) unsigned int*)l,
      16, 0, 0);
}

__device__ __forceinline__ unsigned short f2bf_u(float f) {
  __bf16 h = (__bf16)f;
  return __builtin_bit_cast(unsigned short, h);
}

// ---------------------------------------------------------------------------
// prep_hidden: one block per row i (B*S = 8192). Converts hidden row to bf16,
// computes xu = h.U[:1024]+U[1024], xv = h.V[:1024]+V[1024].
// Stores aL[i] = (xu/8)*log2e, vArr[i] = xv.
// ---------------------------------------------------------------------------
__global__ void __launch_bounds__(256) prep_hidden(
    const float* __restrict__ hidden, const float* __restrict__ U,
    const float* __restrict__ V, unsigned short* __restrict__ hbf,
    float* __restrict__ aL, float* __restrict__ vArr) {
  int row = blockIdx.x;
  int tid = threadIdx.x;
  const float* hr = hidden + (size_t)row * 1024;
  float4 x = *(const float4*)&hr[tid * 4];
  float4 u = *(const float4*)&U[tid * 4];
  float4 v = *(const float4*)&V[tid * 4];
  ushort4 hb;
  hb.x = f2bf_u(x.x); hb.y = f2bf_u(x.y); hb.z = f2bf_u(x.z); hb.w = f2bf_u(x.w);
  *(ushort4*)&hbf[(size_t)row * 1024 + tid * 4] = hb;
  float su = x.x * u.x + x.y * u.y + x.z * u.z + x.w * u.w;
  float sv = x.x * v.x + x.y * v.y + x.z * v.z + x.w * v.w;
  for (int off = 32; off > 0; off >>= 1) {
    su += __shfl_down(su, off);
    sv += __shfl_down(sv, off);
  }
  __shared__ float red[8];
  int lane = tid & 63, w = tid >> 6;
  if (lane == 0) { red[w] = su; red[4 + w] = sv; }
  __syncthreads();
  if (tid == 0) {
    float xu = red[0] + red[1] + red[2] + red[3] + U[1024];
    float xv = red[4] + red[5] + red[6] + red[7] + V[1024];
    aL[row] = xu * 0.125f * LOG2E;
    vArr[row] = xv;
  }
}

// ---------------------------------------------------------------------------
__global__ void __launch_bounds__(256) prep_w(const float* __restrict__ w,
                                              unsigned short* __restrict__ wbf) {
  int idx = (blockIdx.x * 256 + threadIdx.x) * 4;
  float4 x = *(const float4*)&w[idx];
  ushort4 hb;
  hb.x = f2bf_u(x.x); hb.y = f2bf_u(x.y); hb.z = f2bf_u(x.z); hb.w = f2bf_u(x.w);
  *(ushort4*)&wbf[idx] = hb;
}

__global__ void __launch_bounds__(256) prep_mask(const float* __restrict__ mask,
                                                 float* __restrict__ mL) {
  int i = blockIdx.x * 256 + threadIdx.x;
  mL[i] = mask[i] * LOG2E;
}

// ---------------------------------------------------------------------------
// stats: one block per row i. mx2[i] = max_t(aL*v+mL) (log2 domain),
// invZ[i] = 1/sum_t exp2(... - mx2).
// ---------------------------------------------------------------------------
__global__ void __launch_bounds__(256) stats(
    const float* __restrict__ aL, const float* __restrict__ vArr,
    const float* __restrict__ mL, float* __restrict__ mx2,
    float* __restrict__ invZ) {
  int i = blockIdx.x;
  int tbase = (i >> 11) << 11;
  int tid = threadIdx.x;
  float a = aL[i];
  float mloc = -3.0e38f;
#pragma unroll
  for (int c = 0; c < 8; ++c) {
    int t = c * 256 + tid;
    mloc = fmaxf(mloc, fmaf(a, vArr[tbase + t], mL[tbase + t]));
  }
  for (int off = 32; off > 0; off >>= 1) mloc = fmaxf(mloc, __shfl_down(mloc, off));
  __shared__ float red[8];
  int lane = tid & 63, w = tid >> 6;
  if (lane == 0) red[w] = mloc;
  __syncthreads();
  float mx = fmaxf(fmaxf(red[0], red[1]), fmaxf(red[2], red[3]));
  float z = 0.f;
#pragma unroll
  for (int c = 0; c < 8; ++c) {
    int t = c * 256 + tid;
    z += __builtin_amdgcn_exp2f(fmaf(a, vArr[tbase + t], mL[tbase + t]) - mx);
  }
  for (int off = 32; off > 0; off >>= 1) z += __shfl_down(z, off);
  if (lane == 0) red[4 + w] = z;
  __syncthreads();
  if (tid == 0) {
    mx2[i] = mx;
    invZ[i] = 1.0f / (red[4] + red[5] + red[6] + red[7]);
  }
}

// ---------------------------------------------------------------------------
// gemm_vl: VL = hbf @ Wbf^T + bias, stored TRANSPOSED as bf16: vlt[h][i],
// i = global row (8192), pitch 8192. M=8192 N=1024 K=1024.
// 128x128 tile, 4 waves (2x2), 16x16x32 MFMA, BK=32, XOR-swizzled LDS chunks.
// ---------------------------------------------------------------------------
__global__ void __launch_bounds__(256) gemm_vl(
    const unsigned short* __restrict__ hbf, const unsigned short* __restrict__ wbf,
    const float* __restrict__ bias, unsigned short* __restrict__ vlt) {
  __shared__ __align__(16) char sA[128 * 64];
  __shared__ __align__(16) char sB[128 * 64];
  int tid = threadIdx.x;
  int lane = tid & 63, wave = tid >> 6;
  int m0 = blockIdx.y * 128;
  int n0 = blockIdx.x * 128;
  int sr = lane >> 2, sc = lane & 3;
  int wr = wave >> 1, wc = wave & 1;
  int m_ = lane & 15, q = lane >> 4;
  int e = (m_ >> 1) & 3;
  const char* arp = sA + ((wr * 64 + m_) * 64) + ((q ^ e) * 16);
  const char* brp = sB + ((wc * 64 + m_) * 64) + ((q ^ e) * 16);
  f32x4 acc[4][4] = {};
  for (int k0 = 0; k0 < 1024; k0 += 32) {
    __syncthreads();
#pragma unroll
    for (int ii = 0; ii < 2; ++ii) {
      int r0 = wave * 32 + ii * 16;
      int r = r0 + sr;
      int cg = sc ^ ((r >> 1) & 3);
      g2lds16(hbf + ((size_t)(m0 + r) * 1024 + k0 + cg * 8), sA + r0 * 64);
      g2lds16(wbf + ((size_t)(n0 + r) * 1024 + k0 + cg * 8), sB + r0 * 64);
    }
    __syncthreads();
    bf16x8 af[4], bfr[4];
#pragma unroll
    for (int i = 0; i < 4; ++i) af[i] = *(const bf16x8*)(arp + i * 1024);
#pragma unroll
    for (int j = 0; j < 4; ++j) bfr[j] = *(const bf16x8*)(brp + j * 1024);
#pragma unroll
    for (int i = 0; i < 4; ++i)
#pragma unroll
      for (int j = 0; j < 4; ++j)
        acc[i][j] = __builtin_amdgcn_mfma_f32_16x16x32_bf16(af[i], bfr[j], acc[i][j], 0, 0, 0);
  }
  // epilogue: vlt[j][i] = bf16(acc + bias[j]); 4 consecutive i per lane -> 8B store
#pragma unroll
  for (int jt = 0; jt < 4; ++jt) {
    int j = n0 + wc * 64 + jt * 16 + m_;
    float bj = bias[j];
#pragma unroll
    for (int it = 0; it < 4; ++it) {
      int i = m0 + wr * 64 + it * 16 + q * 4;
      f32x4 a = acc[it][jt];
      ushort4 o;
      o.x = f2bf_u(a.x + bj); o.y = f2bf_u(a.y + bj);
      o.z = f2bf_u(a.z + bj); o.w = f2bf_u(a.w + bj);
      *(ushort4*)&vlt[(size_t)j * 8192 + i] = o;
    }
  }
}

// ---------------------------------------------------------------------------
// attn: per batch b: C[s][h] = sum_t P[s][t] * VL[t][h], P generated on the
// fly into the A tile (bf16), B = vlt (VL^T) via global_load_lds.
// Epilogue multiplies by invZ[s] and writes fp32 to out.
// ---------------------------------------------------------------------------
__global__ void __launch_bounds__(256) attn(
    const unsigned short* __restrict__ vlt, const float* __restrict__ aL,
    const float* __restrict__ vArr, const float* __restrict__ mL,
    const float* __restrict__ mx2, const float* __restrict__ invZ,
    float* __restrict__ out) {
  __shared__ __align__(16) char sA[128 * 64];
  __shared__ __align__(16) char sB[128 * 64];
  __shared__ __align__(16) float sV[2048];
  __shared__ __align__(16) float sM[2048];
  int tid = threadIdx.x;
  int lane = tid & 63, wave = tid >> 6;
  int b = blockIdx.z;
  int s0 = blockIdx.y * 128;
  int h0 = blockIdx.x * 128;
  int tbase = b << 11;
  // preload per-batch v and mask arrays into LDS
#pragma unroll
  for (int c = 0; c < 2; ++c) {
    int t4 = (c * 256 + tid) * 4;
    *(float4*)&sV[t4] = *(const float4*)&vArr[tbase + t4];
    *(float4*)&sM[t4] = *(const float4*)&mL[tbase + t4];
  }
  // A-staging constants: thread handles row arow, two 8-elem chunks
  int arow = tid >> 1;
  int c0 = (tid & 1) * 2;
  int grow = tbase + s0 + arow;
  float a_r = aL[grow];
  float mx_r = mx2[grow];
  int e_r = (arow >> 1) & 3;
  char* aw0 = sA + arow * 64 + ((c0 ^ e_r) * 16);
  char* aw1 = sA + arow * 64 + (((c0 + 1) ^ e_r) * 16);
  int kloc0 = c0 * 8;  // 0 or 16
  int sr = lane >> 2, sc = lane & 3;
  int wr = wave >> 1, wc = wave & 1;
  int m_ = lane & 15, q = lane >> 4;
  int e = (m_ >> 1) & 3;
  const char* arp = sA + ((wr * 64 + m_) * 64) + ((q ^ e) * 16);
  const char* brp = sB + ((wc * 64 + m_) * 64) + ((q ^ e) * 16);
  f32x4 acc[4][4] = {};
  __syncthreads();
  for (int k0 = 0; k0 < 2048; k0 += 32) {
    // ---- A stage: 16 probabilities -> bf16 -> 2x ds_write_b128
    int kb = k0 + kloc0;
    const float4* vp = (const float4*)&sV[kb];
    const float4* mp = (const float4*)&sM[kb];
    float pe[16];
#pragma unroll
    for (int u = 0; u < 4; ++u) {
      float4 vv = vp[u];
      float4 mm = mp[u];
      pe[u * 4 + 0] = __builtin_amdgcn_exp2f(fmaf(a_r, vv.x, mm.x) - mx_r);
      pe[u * 4 + 1] = __builtin_amdgcn_exp2f(fmaf(a_r, vv.y, mm.y) - mx_r);
      pe[u * 4 + 2] = __builtin_amdgcn_exp2f(fmaf(a_r, vv.z, mm.z) - mx_r);
      pe[u * 4 + 3] = __builtin_amdgcn_exp2f(fmaf(a_r, vv.w, mm.w) - mx_r);
    }
    bf16x8 p0, p1;
#pragma unroll
    for (int u = 0; u < 8; ++u) {
      p0[u] = (__bf16)pe[u];
      p1[u] = (__bf16)pe[8 + u];
    }
    *(bf16x8*)aw0 = p0;
    *(bf16x8*)aw1 = p1;
    // ---- B stage: VL^T tile via global_load_lds
#pragma unroll
    for (int ii = 0; ii < 2; ++ii) {
      int r0 = wave * 32 + ii * 16;
      int r = r0 + sr;
      int cg = sc ^ ((r >> 1) & 3);
      g2lds16(vlt + ((size_t)(h0 + r) * 8192 + tbase + k0 + cg * 8), sB + r0 * 64);
    }
    __syncthreads();
    bf16x8 af[4], bfr[4];
#pragma unroll
    for (int i = 0; i < 4; ++i) af[i] = *(const bf16x8*)(arp + i * 1024);
#pragma unroll
    for (int j = 0; j < 4; ++j) bfr[j] = *(const bf16x8*)(brp + j * 1024);
#pragma unroll
    for (int i = 0; i < 4; ++i)
#pragma unroll
      for (int j = 0; j < 4; ++j)
        acc[i][j] = __builtin_amdgcn_mfma_f32_16x16x32_bf16(af[i], bfr[j], acc[i][j], 0, 0, 0);
    __syncthreads();
  }
  // epilogue: out[(tbase+s)*1024 + h] = acc * invZ[s]
#pragma unroll
  for (int it = 0; it < 4; ++it) {
    int gi = tbase + s0 + wr * 64 + it * 16 + q * 4;
    float4 z = *(const float4*)&invZ[gi];
#pragma unroll
    for (int jt = 0; jt < 4; ++jt) {
      int h = h0 + wc * 64 + jt * 16 + m_;
      f32x4 a = acc[it][jt];
      out[(size_t)(gi + 0) * 1024 + h] = a.x * z.x;
      out[(size_t)(gi + 1) * 1024 + h] = a.y * z.y;
      out[(size_t)(gi + 2) * 1024 + h] = a.z * z.z;
      out[(size_t)(gi + 3) * 1024 + h] = a.w * z.w;
    }
  }
}

// ---------------------------------------------------------------------------
extern "C" void kernel_launch(void* const* d_in, const int* in_sizes, int n_in,
                              void* d_out, int out_size, void* d_ws, size_t ws_size,
                              hipStream_t stream) {
  const float* hidden = (const float*)d_in[0];
  const float* mask   = (const float*)d_in[1];
  const float* vw     = (const float*)d_in[2];
  const float* vb     = (const float*)d_in[3];
  const float* U      = (const float*)d_in[4];
  const float* V      = (const float*)d_in[5];
  float* out = (float*)d_out;
  char* ws = (char*)d_ws;

  unsigned short* hbf = (unsigned short*)ws;                          // 16 MiB
  unsigned short* wbf = (unsigned short*)(ws + 16777216);             // 2 MiB
  unsigned short* vlt = (unsigned short*)(ws + 16777216 + 2097152);   // 16 MiB
  float* aL   = (float*)(ws + 35651584);
  float* vArr = aL + 8192;
  float* mLa  = vArr + 8192;
  float* mxa  = mLa + 8192;
  float* iZ   = mxa + 8192;

  prep_hidden<<<8192, 256, 0, stream>>>(hidden, U, V, hbf, aL, vArr);
  prep_w<<<1024, 256, 0, stream>>>(vw, wbf);
  prep_mask<<<32, 256, 0, stream>>>(mask, mLa);
  stats<<<8192, 256, 0, stream>>>(aL, vArr, mLa, mxa, iZ);
  gemm_vl<<<dim3(8, 64), 256, 0, stream>>>(hbf, wbf, vb, vlt);
  attn<<<dim3(8, 16, 4), 256, 0, stream>>>(vlt, aL, vArr, mLa, mxa, iZ, out);
}